// Round 1
// baseline (10334.272 us; speedup 1.0000x reference)
//
#include <hip/hip_runtime.h>
#include <math.h>

// ---------------------------------------------------------------------------
// SRRNN: state-regularized GRU.  B=64, S=512, I=256, H=512, K=256, TEMP=1.
//
// Design (round 0):
//  - Precompute SWT = W_hh @ states^T  [1536x256] and Gh0 = h_0 @ W_hh^T [64x1536].
//    Since h_t = p_t @ states for t>=1, gh_{t+1} = p_t @ SWT^T (K=256 not 512).
//  - Main persistent kernel: 8 groups x 32 blocks (256 blocks == 256 CUs,
//    LDS ~138KB forces 1 block/CU -> co-residency). Group owns 8 batches.
//    Each CU owns 16 H-dims (48 of 1536 gate rows); weights for those rows
//    live in LDS. Per step: gi/gh GEMMs (LDS weights), gates, partial
//    squared-distances over owned dims, cross-CU reduce (2 flag barriers),
//    softmax (redundant per CU), h_new over owned dims.
//  - All cross-block traffic via agent-scope atomics (XCD L2s non-coherent).
// ---------------------------------------------------------------------------

#define B_ 64
#define S_ 512
#define I_ 256
#define H_ 512
#define K_ 256
#define G3H 1536
#define NG 8      // groups
#define GC 32     // CUs (blocks) per group
#define GB 8      // batches per group
#define TPB 512

#define WPAD 260  // wT row stride in floats (48 rows x 256 k, padded)
#define SPAD 20   // states-slice row stride in floats (256 k x 16 dims, padded)

// workspace layout (bytes)
#define WS_FLAGS 0
#define WS_FLAGS_SZ (NG * 2 * GC * 4)                  // 2048
#define WS_SWT 2048
#define WS_SWT_SZ (G3H * K_ * 4)                       // 1572864
#define WS_GH0 (WS_SWT + WS_SWT_SZ)
#define WS_GH0_SZ (B_ * G3H * 4)                       // 393216
#define WS_DPART (WS_GH0 + WS_GH0_SZ)
#define WS_DPART_SZ (NG * GC * GB * K_ * 4)            // 2097152
#define WS_DRED (WS_DPART + WS_DPART_SZ)
#define WS_DRED_SZ (NG * GB * K_ * 4)                  // 65536

#define SMEM_FLOATS (2 * 48 * WPAD + K_ * SPAD + 2048 + 2048 + 384 + 384 + 128 + 128 + 48 + 48)
#define SMEM_BYTES (SMEM_FLOATS * 4)                   // 141184

#define OUT_OFF_HN (B_ * S_ * H_)                      // 16777216
#define OUT_OFF_P (OUT_OFF_HN + B_ * H_)               // 16809984

// ---------------------------------------------------------------------------
__global__ void kernel_swt(const float* __restrict__ Whh,
                           const float* __restrict__ states,
                           float* __restrict__ SWT) {
  // SWT[r][k] = sum_j Whh[r][j] * states[k][j];  block handles 8 rows.
  int r0 = blockIdx.x * 8;
  int k = threadIdx.x;  // 0..255
  const float* sr = states + (size_t)k * H_;
  float acc[8];
#pragma unroll
  for (int q = 0; q < 8; ++q) acc[q] = 0.f;
  for (int j = 0; j < H_; ++j) {
    float sv = sr[j];
#pragma unroll
    for (int q = 0; q < 8; ++q) acc[q] += Whh[(size_t)(r0 + q) * H_ + j] * sv;
  }
#pragma unroll
  for (int q = 0; q < 8; ++q) SWT[(size_t)(r0 + q) * K_ + k] = acc[q];
}

__global__ void kernel_gh0(const float* __restrict__ Whh,
                           const float* __restrict__ h0,
                           float* __restrict__ Gh0) {
  // Gh0[b][r] = sum_j h0[b][j] * Whh[r][j]
  int b = blockIdx.x;
  int tid = threadIdx.x;  // 256
  __shared__ float h[H_];
  for (int e = tid; e < H_; e += 256) h[e] = h0[(size_t)b * H_ + e];
  __syncthreads();
  for (int r = tid; r < G3H; r += 256) {
    const float* wr = Whh + (size_t)r * H_;
    float acc = 0.f;
    for (int j = 0; j < H_; ++j) acc += wr[j] * h[j];
    Gh0[(size_t)b * G3H + r] = acc;
  }
}

// ---------------------------------------------------------------------------
__device__ __forceinline__ void gbarrier(unsigned int* f, int cu,
                                         unsigned int target, int tid) {
  __syncthreads();  // drains each wave's vmcnt -> all agent-scope stores done
  if (tid == 0) {
    __hip_atomic_store(f + cu, target, __ATOMIC_RELEASE, __HIP_MEMORY_SCOPE_AGENT);
  }
  if (tid < GC) {
    while (__hip_atomic_load(f + tid, __ATOMIC_RELAXED, __HIP_MEMORY_SCOPE_AGENT) < target) {
      __builtin_amdgcn_s_sleep(1);
    }
  }
  __syncthreads();
}

__global__ __launch_bounds__(TPB) void srrnn_main(
    const float* __restrict__ input, const float* __restrict__ h0,
    const float* __restrict__ W_ih, const float* __restrict__ bias_ih,
    const float* __restrict__ bias_hh, const float* __restrict__ states,
    const float* __restrict__ SWT, const float* __restrict__ Gh0,
    float* __restrict__ dpart, float* __restrict__ dred, unsigned int* flags,
    float* __restrict__ out, float* __restrict__ hn, float* __restrict__ probs) {
  const int tid = threadIdx.x;
  const int g = blockIdx.x >> 5;   // group
  const int cu = blockIdx.x & 31;  // block within group

  extern __shared__ float smem[];
  float* wT_ih = smem;                    // [48][WPAD]
  float* wT_hh = wT_ih + 48 * WPAD;       // [48][WPAD]
  float* s_sl = wT_hh + 48 * WPAD;        // [256][SPAD] (16 owned dims)
  float* x_sl = s_sl + K_ * SPAD;         // [8][256]  (aliased as d_sl in phase 6)
  float* p_sl = x_sl + 2048;              // [8][256]
  float* gi_sl = p_sl + 2048;             // [8][48]
  float* gh_sl = gi_sl + 384;             // [8][48]
  float* hc_sl = gh_sl + 384;             // [8][16]
  float* hp_sl = hc_sl + 128;             // [8][16]
  float* bih_sl = hp_sl + 128;            // [48]
  float* bhh_sl = bih_sl + 48;            // [48]

  // ---- setup: load weight slices / states slice / biases / h0 / gh(t=0) ----
  for (int e = tid; e < 48 * 256; e += TPB) {
    int r = e >> 8, k = e & 255;
    int grow = ((r >> 4) << 9) + (cu << 4) + (r & 15);
    wT_ih[r * WPAD + k] = W_ih[(size_t)grow * I_ + k];
    wT_hh[r * WPAD + k] = SWT[(size_t)grow * K_ + k];
  }
  for (int e = tid; e < K_ * 16; e += TPB) {
    int k = e >> 4, d = e & 15;
    s_sl[k * SPAD + d] = states[((size_t)k << 9) + (cu << 4) + d];
  }
  if (tid < 48) {
    int grow = ((tid >> 4) << 9) + (cu << 4) + (tid & 15);
    bih_sl[tid] = bias_ih[grow];
    bhh_sl[tid] = bias_hh[grow];
  }
  if (tid < 128) {
    int b = tid >> 4, d = tid & 15;
    hp_sl[tid] = h0[((size_t)(g * GB + b) << 9) + (cu << 4) + d];
  }
  if (tid < 384) {
    int b = tid / 48, r = tid % 48;
    int grow = ((r >> 4) << 9) + (cu << 4) + (r & 15);
    gh_sl[b * 48 + r] = Gh0[(size_t)(g * GB + b) * G3H + grow];
  }
  __syncthreads();

  const int wg = tid >> 6;    // wave id 0..7
  const int lane = tid & 63;
  const int mat = wg & 1;     // 0: gi (x @ W_ih^T), 1: gh (p @ SWT^T)
  const int bp = wg >> 1;     // batch pair 0..3

  for (int t = 0; t < S_; ++t) {
    // phase 1: stage x_t
    for (int e = tid; e < GB * I_; e += TPB) {
      int b = e >> 8, k = e & 255;
      x_sl[e] = input[(((size_t)(g * GB + b) * S_ + t) << 8) + k];
    }
    __syncthreads();

    // phase 2: gi / gh GEMMs from LDS weights (2 batches per wave)
    if (lane < 48 && (mat == 0 || t > 0)) {
      const float* wrow = (mat ? wT_hh : wT_ih) + lane * WPAD;
      const float* in0 = (mat ? p_sl : x_sl) + (2 * bp) * 256;
      const float* in1 = in0 + 256;
      float a0 = 0.f, a1 = 0.f;
#pragma unroll 8
      for (int kk = 0; kk < 256; kk += 4) {
        float4 w4 = *(const float4*)(wrow + kk);
        float4 i0 = *(const float4*)(in0 + kk);
        float4 i1 = *(const float4*)(in1 + kk);
        a0 += w4.x * i0.x + w4.y * i0.y + w4.z * i0.z + w4.w * i0.w;
        a1 += w4.x * i1.x + w4.y * i1.y + w4.z * i1.z + w4.w * i1.w;
      }
      float* o = mat ? gh_sl : gi_sl;
      o[(2 * bp) * 48 + lane] = a0;
      o[(2 * bp + 1) * 48 + lane] = a1;
    }
    __syncthreads();

    // phase 3: gates + h_cand over owned 16 dims
    if (tid < 128) {
      int b = tid >> 4, d = tid & 15;
      float gir = gi_sl[b * 48 + d] + bih_sl[d];
      float giz = gi_sl[b * 48 + 16 + d] + bih_sl[16 + d];
      float gin = gi_sl[b * 48 + 32 + d] + bih_sl[32 + d];
      float ghr = gh_sl[b * 48 + d] + bhh_sl[d];
      float ghz = gh_sl[b * 48 + 16 + d] + bhh_sl[16 + d];
      float ghn = gh_sl[b * 48 + 32 + d] + bhh_sl[32 + d];
      float r = 1.f / (1.f + expf(-(gir + ghr)));
      float z = 1.f / (1.f + expf(-(giz + ghz)));
      float n = tanhf(gin + r * ghn);
      hc_sl[tid] = (1.f - z) * n + z * hp_sl[tid];
    }
    __syncthreads();

    // phase 4: partial squared distances over owned 16 dims (wave wg = batch)
    {
      const float4* hcp = (const float4*)(hc_sl + wg * 16);
      float4 hA = hcp[0], hB = hcp[1], hC = hcp[2], hD = hcp[3];
      float* dpb = dpart + ((size_t)(g * GC + cu) * GB + wg) * K_;
#pragma unroll
      for (int j = 0; j < 4; ++j) {
        int k = lane + 64 * j;
        const float4* srp = (const float4*)(s_sl + k * SPAD);
        float4 sA = srp[0], sB = srp[1], sC = srp[2], sD = srp[3];
        float e, acc;
        e = hA.x - sA.x; acc = e * e;
        e = hA.y - sA.y; acc += e * e;
        e = hA.z - sA.z; acc += e * e;
        e = hA.w - sA.w; acc += e * e;
        e = hB.x - sB.x; acc += e * e;
        e = hB.y - sB.y; acc += e * e;
        e = hB.z - sB.z; acc += e * e;
        e = hB.w - sB.w; acc += e * e;
        e = hC.x - sC.x; acc += e * e;
        e = hC.y - sC.y; acc += e * e;
        e = hC.z - sC.z; acc += e * e;
        e = hC.w - sC.w; acc += e * e;
        e = hD.x - sD.x; acc += e * e;
        e = hD.y - sD.y; acc += e * e;
        e = hD.z - sD.z; acc += e * e;
        e = hD.w - sD.w; acc += e * e;
        __hip_atomic_store(dpb + k, acc, __ATOMIC_RELAXED, __HIP_MEMORY_SCOPE_AGENT);
      }
    }
    gbarrier(flags + (g * 2 + 0) * GC, cu, (unsigned)(t + 1), tid);

    // phase 5: reduce own 8-k slice across the 32 CUs
    if (tid < 64) {
      int b = tid >> 3, kk = tid & 7;
      int k = (cu << 3) + kk;
      const float* base = dpart + (size_t)g * GC * GB * K_ + b * K_ + k;
      float s = 0.f;
#pragma unroll 8
      for (int c2 = 0; c2 < GC; ++c2)
        s += __hip_atomic_load(base + (size_t)c2 * GB * K_, __ATOMIC_RELAXED,
                               __HIP_MEMORY_SCOPE_AGENT);
      __hip_atomic_store(dred + (size_t)(g * GB + b) * K_ + k, s,
                         __ATOMIC_RELAXED, __HIP_MEMORY_SCOPE_AGENT);
    }
    gbarrier(flags + (g * 2 + 1) * GC, cu, (unsigned)(t + 1), tid);

    // phase 6: read full d, softmax (redundant per CU), p + probs
    for (int e = tid; e < GB * K_; e += TPB)
      x_sl[e] = __hip_atomic_load(dred + (size_t)g * GB * K_ + e,
                                  __ATOMIC_RELAXED, __HIP_MEMORY_SCOPE_AGENT);
    __syncthreads();
    {
      const float* db = x_sl + wg * K_;
      float d0 = db[lane], d1 = db[lane + 64], d2 = db[lane + 128], d3 = db[lane + 192];
      float m = fminf(fminf(d0, d1), fminf(d2, d3));
#pragma unroll
      for (int off = 32; off >= 1; off >>= 1) m = fminf(m, __shfl_xor(m, off));
      float e0 = expf(m - d0), e1 = expf(m - d1), e2 = expf(m - d2), e3 = expf(m - d3);
      float s = e0 + e1 + e2 + e3;
#pragma unroll
      for (int off = 32; off >= 1; off >>= 1) s += __shfl_xor(s, off);
      float inv = 1.f / s;
      e0 *= inv; e1 *= inv; e2 *= inv; e3 *= inv;
      float* pb = p_sl + wg * K_;
      pb[lane] = e0; pb[lane + 64] = e1; pb[lane + 128] = e2; pb[lane + 192] = e3;
      if (cu == 0) {
        float* pr = probs + ((size_t)(g * GB + wg) * S_ + t) * K_;
        pr[lane] = e0; pr[lane + 64] = e1; pr[lane + 128] = e2; pr[lane + 192] = e3;
      }
    }
    __syncthreads();

    // phase 7: h_new over owned 16 dims (split K four ways, shfl reduce)
    {
      int d = lane & 15, q = lane >> 4;
      float acc = 0.f;
      const float* pb = p_sl + wg * K_;
#pragma unroll 4
      for (int i = 0; i < 64; ++i) {
        int k = (q << 6) + i;
        acc += pb[k] * s_sl[k * SPAD + d];
      }
      acc += __shfl_xor(acc, 32);
      acc += __shfl_xor(acc, 16);
      if (q == 0) {
        hp_sl[wg * 16 + d] = acc;
        out[(((size_t)(g * GB + wg) * S_ + t) << 9) + (cu << 4) + d] = acc;
      }
    }
    __syncthreads();
  }

  // final hidden state
  if (tid < 128) {
    int b = tid >> 4, d = tid & 15;
    hn[((size_t)(g * GB + b) << 9) + (cu << 4) + d] = hp_sl[tid];
  }
}

// ---------------------------------------------------------------------------
extern "C" void kernel_launch(void* const* d_in, const int* in_sizes, int n_in,
                              void* d_out, int out_size, void* d_ws, size_t ws_size,
                              hipStream_t stream) {
  const float* input = (const float*)d_in[0];
  const float* h0 = (const float*)d_in[1];
  const float* W_ih = (const float*)d_in[2];
  const float* W_hh = (const float*)d_in[3];
  const float* bias_ih = (const float*)d_in[4];
  const float* bias_hh = (const float*)d_in[5];
  const float* states = (const float*)d_in[6];
  float* out = (float*)d_out;

  char* ws = (char*)d_ws;
  unsigned int* flags = (unsigned int*)(ws + WS_FLAGS);
  float* SWT = (float*)(ws + WS_SWT);
  float* Gh0 = (float*)(ws + WS_GH0);
  float* dpart = (float*)(ws + WS_DPART);
  float* dred = (float*)(ws + WS_DRED);

  hipMemsetAsync(d_ws, 0, WS_FLAGS_SZ, stream);  // barrier flags -> 0 each launch
  kernel_swt<<<G3H / 8, 256, 0, stream>>>(W_hh, states, SWT);
  kernel_gh0<<<B_, 256, 0, stream>>>(W_hh, h0, Gh0);

  hipFuncSetAttribute(reinterpret_cast<const void*>(srrnn_main),
                      hipFuncAttributeMaxDynamicSharedMemorySize, SMEM_BYTES);
  srrnn_main<<<NG * GC, TPB, SMEM_BYTES, stream>>>(
      input, h0, W_ih, bias_ih, bias_hh, states, SWT, Gh0, dpart, dred, flags,
      out, out + OUT_OFF_HN, out + OUT_OFF_P);
}